// Round 1
// 142.276 us; speedup vs baseline: 2.0648x; 2.0648x over previous
//
#include <hip/hip_runtime.h>
#include <math.h>

#define BB 32
#define CC 512      // = L (sequence length)
#define HW 4096
#define DM 32       // d_model
#define DI 32       // d_inner
#define DS 8        // d_state
#define KC 4        // conv kernel

__device__ __forceinline__ float siluf(float x) {
    return x / (1.0f + __expf(-x));
}
__device__ __forceinline__ float softplusf(float x) {
    // log(1+exp(x)) numerically stable
    float ax = fabsf(x);
    return fmaxf(x, 0.0f) + log1pf(__expf(-ax));
}

// ---------------- Kernel 1: global avg + max pool over H*W=4096 ----------------
__global__ __launch_bounds__(256) void pool_kernel(const float* __restrict__ x,
                                                   float* __restrict__ avg,
                                                   float* __restrict__ mx) {
    int bc = blockIdx.x;                       // b*512 + c
    const float4* xp = reinterpret_cast<const float4*>(x + (size_t)bc * HW);
    int tid = threadIdx.x;
    float s = 0.f, m = -INFINITY;
#pragma unroll
    for (int r = 0; r < 4; ++r) {
        float4 v = xp[r * 256 + tid];
        s += (v.x + v.y) + (v.z + v.w);
        m = fmaxf(m, fmaxf(fmaxf(v.x, v.y), fmaxf(v.z, v.w)));
    }
    // wave64 reduce
    for (int off = 32; off > 0; off >>= 1) {
        s += __shfl_down(s, off);
        m = fmaxf(m, __shfl_down(m, off));
    }
    __shared__ float ss[4], sm[4];
    int wave = tid >> 6;
    if ((tid & 63) == 0) { ss[wave] = s; sm[wave] = m; }
    __syncthreads();
    if (tid == 0) {
        float S = (ss[0] + ss[1]) + (ss[2] + ss[3]);
        float M = fmaxf(fmaxf(sm[0], sm[1]), fmaxf(sm[2], sm[3]));
        avg[bc] = S * (1.0f / HW);
        mx[bc]  = M;
    }
}

// ---------------- Kernel 2: lin1 + layernorm + in_proj -> xz [B][64][512] ----------------
__global__ __launch_bounds__(256) void hproj_kernel(
    const float* __restrict__ avg, const float* __restrict__ mx,
    const float* __restrict__ lin1_w, const float* __restrict__ lin1_b,
    const float* __restrict__ ln1_g, const float* __restrict__ ln1_b,
    const float* __restrict__ in_proj_w, float* __restrict__ xz)
{
    __shared__ float sW[64 * DM];
    int tid = threadIdx.x;
    for (int i = tid; i < 64 * DM; i += 256) sW[i] = in_proj_w[i];
    __syncthreads();
    int g = blockIdx.x * 256 + tid;     // b*512 + l   (l == c)
    int b = g >> 9, l = g & 511;
    float a = avg[g], M = mx[g];
    float h[DM];
    float mean = 0.f;
#pragma unroll
    for (int m_ = 0; m_ < DM; ++m_) {
        h[m_] = a * lin1_w[2 * m_] + M * lin1_w[2 * m_ + 1] + lin1_b[m_];
        mean += h[m_];
    }
    mean *= (1.0f / DM);
    float var = 0.f;
#pragma unroll
    for (int m_ = 0; m_ < DM; ++m_) { float d = h[m_] - mean; var += d * d; }
    var *= (1.0f / DM);
    float rs = rsqrtf(var + 1e-5f);
#pragma unroll
    for (int m_ = 0; m_ < DM; ++m_)
        h[m_] = (h[m_] - mean) * rs * ln1_g[m_] + ln1_b[m_];
    for (int e = 0; e < 64; ++e) {
        float acc = 0.f;
#pragma unroll
        for (int m_ = 0; m_ < DM; ++m_) acc += h[m_] * sW[e * DM + m_];
        xz[(((size_t)b * 64 + e) << 9) + l] = acc;
    }
}

// ------- Kernel 3: causal conv1d + silu + x_proj(B,C,dt) + softplus(dtproj), both dirs -------
// thread = one scan position l for (b, dir). Outputs stored l-major (scan order).
__global__ __launch_bounds__(512) void convproj_kernel(
    const float* __restrict__ xz,
    const float* __restrict__ conv_w_f, const float* __restrict__ conv_b_f,
    const float* __restrict__ xproj_w_f, const float* __restrict__ dtproj_w_f,
    const float* __restrict__ dtproj_b_f,
    const float* __restrict__ conv_w_r, const float* __restrict__ conv_b_r,
    const float* __restrict__ xproj_w_r, const float* __restrict__ dtproj_w_r,
    const float* __restrict__ dtproj_b_r,
    float* __restrict__ u_ws, float* __restrict__ dt_ws,
    float* __restrict__ B_ws, float* __restrict__ C_ws)
{
    int bd = blockIdx.x;        // b*2 + dir
    int b = bd >> 1, dir = bd & 1;
    int l = threadIdx.x;        // scan position
    const float* cw = dir ? conv_w_r : conv_w_f;
    const float* cb = dir ? conv_b_r : conv_b_f;
    const float* xw = dir ? xproj_w_r : xproj_w_f;
    const float* dw = dir ? dtproj_w_r : dtproj_w_f;
    const float* db = dir ? dtproj_b_r : dtproj_b_f;

    const float* xzb = xz + (size_t)b * 64 * 512;

    float u[DI];
#pragma unroll
    for (int d = 0; d < DI; ++d) {
        float acc = cb[d];
#pragma unroll
        for (int k = 0; k < KC; ++k) {
            int j = l - 3 + k;                       // scan-space index into flipped/orig seq
            if (j >= 0) {
                int idx = dir ? (511 - j) : j;       // original position
                acc += cw[d * KC + k] * xzb[(d << 9) + idx];
            }
        }
        u[d] = siluf(acc);
    }
    size_t row = (size_t)bd * 512 + l;
#pragma unroll
    for (int d = 0; d < DI; ++d) u_ws[row * DI + d] = u[d];

    float dtr0 = 0.f, dtr1 = 0.f;
#pragma unroll
    for (int d = 0; d < DI; ++d) {
        dtr0 += u[d] * xw[0 * DI + d];
        dtr1 += u[d] * xw[1 * DI + d];
    }
#pragma unroll
    for (int k = 0; k < DS; ++k) {
        float accB = 0.f, accC = 0.f;
#pragma unroll
        for (int d = 0; d < DI; ++d) {
            accB += u[d] * xw[(2 + k) * DI + d];
            accC += u[d] * xw[(10 + k) * DI + d];
        }
        B_ws[row * DS + k] = accB;
        C_ws[row * DS + k] = accC;
    }
#pragma unroll
    for (int d = 0; d < DI; ++d) {
        float v = dtr0 * dw[d * 2] + dtr1 * dw[d * 2 + 1] + db[d];
        dt_ws[row * DI + d] = softplusf(v);
    }
}

// ---------------- Kernel 4: chunked parallel selective scan ----------------
// Block = one (b, dir) pair. 512 threads = 16 chunks x 32 d-channels.
// Each thread keeps all 8 n-states in registers (no cross-lane shuffles).
// Phase 1: local scan of 32 steps per chunk, accumulating (prod dA, h_local).
// Phase 2: serial combine of 16 chunk carries per (d,n) through LDS.
// Phase 3: re-scan each chunk from its exact prefix, emitting y.
#define NCH 16
#define CHL 32
__global__ __launch_bounds__(512) void scan_kernel(
    const float* __restrict__ u_ws, const float* __restrict__ dt_ws,
    const float* __restrict__ B_ws, const float* __restrict__ C_ws,
    const float* __restrict__ A_log_f, const float* __restrict__ D_f,
    const float* __restrict__ A_log_r, const float* __restrict__ D_r,
    float* __restrict__ y_ws)
{
    int bd = blockIdx.x;        // b*2 + dir
    int dir = bd & 1;
    int tid = threadIdx.x;
    int chunk = tid >> 5;       // 0..15
    int d = tid & 31;           // 0..31
    const float* Alog = dir ? A_log_r : A_log_f;
    const float* Dp   = dir ? D_r : D_f;

    float A[DS];
#pragma unroll
    for (int n = 0; n < DS; ++n) A[n] = -__expf(Alog[d * DS + n]);
    float Dd = Dp[d];

    const float* ub  = u_ws  + (size_t)bd * 512 * DI;
    const float* dtb = dt_ws + (size_t)bd * 512 * DI;
    const float* Bb  = B_ws  + (size_t)bd * 512 * DS;
    const float* Cb  = C_ws  + (size_t)bd * 512 * DS;
    float* yb = y_ws + (size_t)bd * 512 * DI;   // stored at ORIGINAL positions

    __shared__ float s_a[NCH][DI][DS];   // 16 KiB
    __shared__ float s_h[NCH][DI][DS];   // 16 KiB

    int l0 = chunk * CHL;
    float h[DS], ap[DS];
#pragma unroll
    for (int n = 0; n < DS; ++n) { h[n] = 0.f; ap[n] = 1.f; }

    // ---- Phase 1: local chunk scan (carry only, no y) ----
#pragma unroll 2
    for (int l = l0; l < l0 + CHL; ++l) {
        float dt = dtb[l * DI + d];
        float uu = ub[l * DI + d];
        float dtu = dt * uu;
#pragma unroll
        for (int n = 0; n < DS; ++n) {
            float dA = __expf(dt * A[n]);
            float bm = Bb[l * DS + n];
            ap[n] *= dA;
            h[n] = dA * h[n] + dtu * bm;
        }
    }
#pragma unroll
    for (int n = 0; n < DS; ++n) {
        s_a[chunk][d][n] = ap[n];
        s_h[chunk][d][n] = h[n];
    }
    __syncthreads();

    // ---- Phase 2: serial combine across chunks, one thread per (d,n) ----
    if (tid < DI * DS) {
        int dd = tid >> 3, nn = tid & 7;
        float hin = 0.f;
#pragma unroll
        for (int j = 0; j < NCH; ++j) {
            float aj = s_a[j][dd][nn];
            float hj = s_h[j][dd][nn];
            s_h[j][dd][nn] = hin;           // overwrite with exact prefix h_in for chunk j
            hin = aj * hin + hj;
        }
    }
    __syncthreads();

    // ---- Phase 3: re-scan chunk from exact prefix, emit y ----
#pragma unroll
    for (int n = 0; n < DS; ++n) h[n] = s_h[chunk][d][n];
#pragma unroll 2
    for (int l = l0; l < l0 + CHL; ++l) {
        float dt = dtb[l * DI + d];
        float uu = ub[l * DI + d];
        float dtu = dt * uu;
        float y = Dd * uu;
#pragma unroll
        for (int n = 0; n < DS; ++n) {
            float dA = __expf(dt * A[n]);
            float bm = Bb[l * DS + n];
            float cm = Cb[l * DS + n];
            h[n] = dA * h[n] + dtu * bm;
            y += h[n] * cm;
        }
        int lo = dir ? (511 - l) : l;
        yb[lo * DI + d] = y;
    }
}

// ---------------- Kernel 5: gate + out_proj + layernorm + sigmoid head ----------------
__global__ __launch_bounds__(256) void final_kernel(
    const float* __restrict__ y_ws, const float* __restrict__ xz,
    const float* __restrict__ out_proj_w, const float* __restrict__ mnorm_g,
    const float* __restrict__ mnorm_b, const float* __restrict__ lin2_w,
    const float* __restrict__ lin2_b, float* __restrict__ out)
{
    __shared__ float sW[DM * DI];
    int tid = threadIdx.x;
    for (int i = tid; i < DM * DI; i += 256) sW[i] = out_proj_w[i];
    __syncthreads();
    int g = blockIdx.x * 256 + tid;   // b*512 + l
    int b = g >> 9, l = g & 511;
    const float* yf = y_ws + ((size_t)(b * 2 + 0) * 512 + l) * DI;
    const float* yr = y_ws + ((size_t)(b * 2 + 1) * 512 + l) * DI;
    float comb[DI];
#pragma unroll
    for (int d = 0; d < DI; ++d) {
        float z = xz[(((size_t)b * 64 + 32 + d) << 9) + l];
        comb[d] = 0.5f * (yf[d] + yr[d]) * siluf(z);
    }
    float o[DM];
    float mean = 0.f;
#pragma unroll
    for (int oo = 0; oo < DM; ++oo) {
        float acc = 0.f;
#pragma unroll
        for (int d = 0; d < DI; ++d) acc += comb[d] * sW[oo * DI + d];
        o[oo] = acc;
        mean += acc;
    }
    mean *= (1.0f / DM);
    float var = 0.f;
#pragma unroll
    for (int oo = 0; oo < DM; ++oo) { float df = o[oo] - mean; var += df * df; }
    var *= (1.0f / DM);
    float rs = rsqrtf(var + 1e-5f);
    float s = lin2_b[0];
#pragma unroll
    for (int oo = 0; oo < DM; ++oo) {
        float v = (o[oo] - mean) * rs * mnorm_g[oo] + mnorm_b[oo];
        s += v * lin2_w[oo];
    }
    float att = 1.0f / (1.0f + __expf(-s));
    out[g] = 0.25f * att + 0.875f;
}

extern "C" void kernel_launch(void* const* d_in, const int* in_sizes, int n_in,
                              void* d_out, int out_size, void* d_ws, size_t ws_size,
                              hipStream_t stream)
{
    const float* x         = (const float*)d_in[0];
    const float* lin1_w    = (const float*)d_in[1];
    const float* lin1_b    = (const float*)d_in[2];
    const float* ln1_g     = (const float*)d_in[3];
    const float* ln1_b     = (const float*)d_in[4];
    const float* in_proj_w = (const float*)d_in[5];
    const float* conv_w_f  = (const float*)d_in[6];
    const float* conv_b_f  = (const float*)d_in[7];
    const float* xproj_w_f = (const float*)d_in[8];
    const float* dtproj_w_f= (const float*)d_in[9];
    const float* dtproj_b_f= (const float*)d_in[10];
    const float* A_log_f   = (const float*)d_in[11];
    const float* D_f       = (const float*)d_in[12];
    const float* conv_w_r  = (const float*)d_in[13];
    const float* conv_b_r  = (const float*)d_in[14];
    const float* xproj_w_r = (const float*)d_in[15];
    const float* dtproj_w_r= (const float*)d_in[16];
    const float* dtproj_b_r= (const float*)d_in[17];
    const float* A_log_r   = (const float*)d_in[18];
    const float* D_r       = (const float*)d_in[19];
    const float* out_proj_w= (const float*)d_in[20];
    const float* mnorm_g   = (const float*)d_in[21];
    const float* mnorm_b   = (const float*)d_in[22];
    const float* lin2_w    = (const float*)d_in[23];
    const float* lin2_b    = (const float*)d_in[24];

    float* ws   = (float*)d_ws;
    float* avg  = ws;                          // 16384
    float* mx   = ws + 16384;                  // 16384
    float* xz   = ws + 32768;                  // 32*64*512   = 1048576
    float* u_ws = xz + 1048576;                // 2*32*512*32 = 1048576
    float* dt_ws= u_ws + 1048576;              // 1048576
    float* B_ws = dt_ws + 1048576;             // 2*32*512*8  = 262144
    float* C_ws = B_ws + 262144;               // 262144
    float* y_ws = C_ws + 262144;               // 1048576
    (void)ws_size; (void)in_sizes; (void)n_in; (void)out_size;

    pool_kernel<<<BB * CC, 256, 0, stream>>>(x, avg, mx);
    hproj_kernel<<<64, 256, 0, stream>>>(avg, mx, lin1_w, lin1_b, ln1_g, ln1_b, in_proj_w, xz);
    convproj_kernel<<<BB * 2, 512, 0, stream>>>(xz, conv_w_f, conv_b_f, xproj_w_f, dtproj_w_f, dtproj_b_f,
                                                conv_w_r, conv_b_r, xproj_w_r, dtproj_w_r, dtproj_b_r,
                                                u_ws, dt_ws, B_ws, C_ws);
    scan_kernel<<<BB * 2, 512, 0, stream>>>(u_ws, dt_ws, B_ws, C_ws, A_log_f, D_f, A_log_r, D_r, y_ws);
    final_kernel<<<64, 256, 0, stream>>>(y_ws, xz, out_proj_w, mnorm_g, mnorm_b, lin2_w, lin2_b,
                                         (float*)d_out);
}

// Round 2
// 125.543 us; speedup vs baseline: 2.3400x; 1.1333x over previous
//
#include <hip/hip_runtime.h>
#include <math.h>

#define BB 32
#define CC 512      // = L (sequence length)
#define HW 4096
#define DM 32       // d_model
#define DI 32       // d_inner
#define DS 8        // d_state
#define KC 4        // conv kernel

__device__ __forceinline__ float siluf(float x) {
    return x / (1.0f + __expf(-x));
}
__device__ __forceinline__ float softplusf(float x) {
    // log(1+exp(x)) numerically stable
    float ax = fabsf(x);
    return fmaxf(x, 0.0f) + log1pf(__expf(-ax));
}

// ---------------- Kernel 1: global avg + max pool over H*W=4096 ----------------
__global__ __launch_bounds__(256) void pool_kernel(const float* __restrict__ x,
                                                   float* __restrict__ avg,
                                                   float* __restrict__ mx) {
    int bc = blockIdx.x;                       // b*512 + c
    const float4* xp = reinterpret_cast<const float4*>(x + (size_t)bc * HW);
    int tid = threadIdx.x;
    float s = 0.f, m = -INFINITY;
#pragma unroll
    for (int r = 0; r < 4; ++r) {
        float4 v = xp[r * 256 + tid];
        s += (v.x + v.y) + (v.z + v.w);
        m = fmaxf(m, fmaxf(fmaxf(v.x, v.y), fmaxf(v.z, v.w)));
    }
    // wave64 reduce
    for (int off = 32; off > 0; off >>= 1) {
        s += __shfl_down(s, off);
        m = fmaxf(m, __shfl_down(m, off));
    }
    __shared__ float ss[4], sm[4];
    int wave = tid >> 6;
    if ((tid & 63) == 0) { ss[wave] = s; sm[wave] = m; }
    __syncthreads();
    if (tid == 0) {
        float S = (ss[0] + ss[1]) + (ss[2] + ss[3]);
        float M = fmaxf(fmaxf(sm[0], sm[1]), fmaxf(sm[2], sm[3]));
        avg[bc] = S * (1.0f / HW);
        mx[bc]  = M;
    }
}

// ---------------- Kernel 2: lin1 + layernorm + in_proj -> xz [B][64][512] ----------------
// grid = 64 l-blocks x 4 e-groups; each block computes 16 of the 64 in_proj rows.
__global__ __launch_bounds__(256) void hproj_kernel(
    const float* __restrict__ avg, const float* __restrict__ mx,
    const float* __restrict__ lin1_w, const float* __restrict__ lin1_b,
    const float* __restrict__ ln1_g, const float* __restrict__ ln1_b,
    const float* __restrict__ in_proj_w, float* __restrict__ xz)
{
    int bx = blockIdx.x;
    int lb = bx >> 2, eg = bx & 3;      // l-block 0..63, e-group 0..3
    __shared__ float sW[16 * DM];
    int tid = threadIdx.x;
    for (int i = tid; i < 16 * DM; i += 256) sW[i] = in_proj_w[eg * 16 * DM + i];
    __syncthreads();
    int g = lb * 256 + tid;             // b*512 + l   (l == c)
    int b = g >> 9, l = g & 511;
    float a = avg[g], M = mx[g];
    float h[DM];
    float mean = 0.f;
#pragma unroll
    for (int m_ = 0; m_ < DM; ++m_) {
        h[m_] = a * lin1_w[2 * m_] + M * lin1_w[2 * m_ + 1] + lin1_b[m_];
        mean += h[m_];
    }
    mean *= (1.0f / DM);
    float var = 0.f;
#pragma unroll
    for (int m_ = 0; m_ < DM; ++m_) { float d = h[m_] - mean; var += d * d; }
    var *= (1.0f / DM);
    float rs = rsqrtf(var + 1e-5f);
#pragma unroll
    for (int m_ = 0; m_ < DM; ++m_)
        h[m_] = (h[m_] - mean) * rs * ln1_g[m_] + ln1_b[m_];
#pragma unroll
    for (int e2 = 0; e2 < 16; ++e2) {
        int e = eg * 16 + e2;
        float acc = 0.f;
#pragma unroll
        for (int m_ = 0; m_ < DM; ++m_) acc += h[m_] * sW[e2 * DM + m_];
        xz[(((size_t)b * 64 + e) << 9) + l] = acc;
    }
}

// ------- Kernel 3: causal conv1d + silu + x_proj(B,C,dt) + softplus(dtproj), both dirs -------
// grid = (b,dir) x 8 l-tiles; thread = one scan position l. Outputs stored l-major.
__global__ __launch_bounds__(64) void convproj_kernel(
    const float* __restrict__ xz,
    const float* __restrict__ conv_w_f, const float* __restrict__ conv_b_f,
    const float* __restrict__ xproj_w_f, const float* __restrict__ dtproj_w_f,
    const float* __restrict__ dtproj_b_f,
    const float* __restrict__ conv_w_r, const float* __restrict__ conv_b_r,
    const float* __restrict__ xproj_w_r, const float* __restrict__ dtproj_w_r,
    const float* __restrict__ dtproj_b_r,
    float* __restrict__ u_ws, float* __restrict__ dt_ws,
    float* __restrict__ B_ws, float* __restrict__ C_ws)
{
    int bx = blockIdx.x;
    int bd = bx >> 3, lt = bx & 7;      // (b,dir), l-tile 0..7
    int b = bd >> 1, dir = bd & 1;
    int l = lt * 64 + threadIdx.x;      // scan position
    const float* cw = dir ? conv_w_r : conv_w_f;
    const float* cb = dir ? conv_b_r : conv_b_f;
    const float* xw = dir ? xproj_w_r : xproj_w_f;
    const float* dw = dir ? dtproj_w_r : dtproj_w_f;
    const float* db = dir ? dtproj_b_r : dtproj_b_f;

    const float* xzb = xz + (size_t)b * 64 * 512;

    float u[DI];
#pragma unroll
    for (int d = 0; d < DI; ++d) {
        float acc = cb[d];
#pragma unroll
        for (int k = 0; k < KC; ++k) {
            int j = l - 3 + k;                       // scan-space index into flipped/orig seq
            if (j >= 0) {
                int idx = dir ? (511 - j) : j;       // original position
                acc += cw[d * KC + k] * xzb[(d << 9) + idx];
            }
        }
        u[d] = siluf(acc);
    }
    size_t row = (size_t)bd * 512 + l;
#pragma unroll
    for (int d = 0; d < DI; ++d) u_ws[row * DI + d] = u[d];

    float dtr0 = 0.f, dtr1 = 0.f;
#pragma unroll
    for (int d = 0; d < DI; ++d) {
        dtr0 += u[d] * xw[0 * DI + d];
        dtr1 += u[d] * xw[1 * DI + d];
    }
#pragma unroll
    for (int k = 0; k < DS; ++k) {
        float accB = 0.f, accC = 0.f;
#pragma unroll
        for (int d = 0; d < DI; ++d) {
            accB += u[d] * xw[(2 + k) * DI + d];
            accC += u[d] * xw[(10 + k) * DI + d];
        }
        B_ws[row * DS + k] = accB;
        C_ws[row * DS + k] = accC;
    }
#pragma unroll
    for (int d = 0; d < DI; ++d) {
        float v = dtr0 * dw[d * 2] + dtr1 * dw[d * 2 + 1] + db[d];
        dt_ws[row * DI + d] = softplusf(v);
    }
}

// ---------------- Kernel 4: chunked parallel selective scan ----------------
// grid = (b,dir) x 4 d-groups; block = 16 chunks x 8 d = 128 threads.
// Each thread keeps all 8 n-states in registers (no cross-lane shuffles).
// Phase 1: local scan of 32 steps per chunk, accumulating (prod dA, h_local).
// Phase 2: serial combine of 16 chunk carries per (d,n) through LDS.
// Phase 3: re-scan each chunk from its exact prefix, emitting y.
#define NCH 16
#define CHL 32
#define DPB 8      // d-channels per block
__global__ __launch_bounds__(128) void scan_kernel(
    const float* __restrict__ u_ws, const float* __restrict__ dt_ws,
    const float* __restrict__ B_ws, const float* __restrict__ C_ws,
    const float* __restrict__ A_log_f, const float* __restrict__ D_f,
    const float* __restrict__ A_log_r, const float* __restrict__ D_r,
    float* __restrict__ y_ws)
{
    int bx = blockIdx.x;
    int bd = bx >> 2, dgroup = bx & 3;  // (b,dir), d-group 0..3
    int dir = bd & 1;
    int tid = threadIdx.x;
    int chunk = tid >> 3;       // 0..15
    int dg = tid & 7;           // 0..7
    int d = dgroup * DPB + dg;
    const float* Alog = dir ? A_log_r : A_log_f;
    const float* Dp   = dir ? D_r : D_f;

    float A[DS];
#pragma unroll
    for (int n = 0; n < DS; ++n) A[n] = -__expf(Alog[d * DS + n]);
    float Dd = Dp[d];

    const float* ub  = u_ws  + (size_t)bd * 512 * DI;
    const float* dtb = dt_ws + (size_t)bd * 512 * DI;
    const float* Bb  = B_ws  + (size_t)bd * 512 * DS;
    const float* Cb  = C_ws  + (size_t)bd * 512 * DS;
    float* yb = y_ws + (size_t)bd * 512 * DI;   // stored at ORIGINAL positions

    __shared__ float s_a[NCH][DPB][DS + 1];   // +1 pad: kill 8-way bank conflict
    __shared__ float s_h[NCH][DPB][DS + 1];

    int l0 = chunk * CHL;
    float h[DS], ap[DS];
#pragma unroll
    for (int n = 0; n < DS; ++n) { h[n] = 0.f; ap[n] = 1.f; }

    // ---- Phase 1: local chunk scan (carry only, no y) ----
#pragma unroll 2
    for (int l = l0; l < l0 + CHL; ++l) {
        float dt = dtb[l * DI + d];
        float uu = ub[l * DI + d];
        float dtu = dt * uu;
#pragma unroll
        for (int n = 0; n < DS; ++n) {
            float dA = __expf(dt * A[n]);
            float bm = Bb[l * DS + n];
            ap[n] *= dA;
            h[n] = dA * h[n] + dtu * bm;
        }
    }
#pragma unroll
    for (int n = 0; n < DS; ++n) {
        s_a[chunk][dg][n] = ap[n];
        s_h[chunk][dg][n] = h[n];
    }
    __syncthreads();

    // ---- Phase 2: serial combine across chunks, one thread per (d,n) ----
    if (tid < DPB * DS) {
        int dd = tid >> 3, nn = tid & 7;
        float hin = 0.f;
#pragma unroll
        for (int j = 0; j < NCH; ++j) {
            float aj = s_a[j][dd][nn];
            float hj = s_h[j][dd][nn];
            s_h[j][dd][nn] = hin;           // overwrite with exact prefix h_in for chunk j
            hin = aj * hin + hj;
        }
    }
    __syncthreads();

    // ---- Phase 3: re-scan chunk from exact prefix, emit y ----
#pragma unroll
    for (int n = 0; n < DS; ++n) h[n] = s_h[chunk][dg][n];
#pragma unroll 2
    for (int l = l0; l < l0 + CHL; ++l) {
        float dt = dtb[l * DI + d];
        float uu = ub[l * DI + d];
        float dtu = dt * uu;
        float y = Dd * uu;
#pragma unroll
        for (int n = 0; n < DS; ++n) {
            float dA = __expf(dt * A[n]);
            float bm = Bb[l * DS + n];
            float cm = Cb[l * DS + n];
            h[n] = dA * h[n] + dtu * bm;
            y += h[n] * cm;
        }
        int lo = dir ? (511 - l) : l;
        yb[lo * DI + d] = y;
    }
}

// ---------------- Kernel 5: gate + out_proj + layernorm + sigmoid head ----------------
// grid = 256 blocks x 64 threads; thread = one (b,l).
__global__ __launch_bounds__(64) void final_kernel(
    const float* __restrict__ y_ws, const float* __restrict__ xz,
    const float* __restrict__ out_proj_w, const float* __restrict__ mnorm_g,
    const float* __restrict__ mnorm_b, const float* __restrict__ lin2_w,
    const float* __restrict__ lin2_b, float* __restrict__ out)
{
    __shared__ float sW[DM * DI];
    int tid = threadIdx.x;
    for (int i = tid; i < DM * DI; i += 64) sW[i] = out_proj_w[i];
    __syncthreads();
    int g = blockIdx.x * 64 + tid;    // b*512 + l
    int b = g >> 9, l = g & 511;
    const float* yf = y_ws + ((size_t)(b * 2 + 0) * 512 + l) * DI;
    const float* yr = y_ws + ((size_t)(b * 2 + 1) * 512 + l) * DI;
    float comb[DI];
#pragma unroll
    for (int d = 0; d < DI; ++d) {
        float z = xz[(((size_t)b * 64 + 32 + d) << 9) + l];
        comb[d] = 0.5f * (yf[d] + yr[d]) * siluf(z);
    }
    float o[DM];
    float mean = 0.f;
#pragma unroll
    for (int oo = 0; oo < DM; ++oo) {
        float acc = 0.f;
#pragma unroll
        for (int d = 0; d < DI; ++d) acc += comb[d] * sW[oo * DI + d];
        o[oo] = acc;
        mean += acc;
    }
    mean *= (1.0f / DM);
    float var = 0.f;
#pragma unroll
    for (int oo = 0; oo < DM; ++oo) { float df = o[oo] - mean; var += df * df; }
    var *= (1.0f / DM);
    float rs = rsqrtf(var + 1e-5f);
    float s = lin2_b[0];
#pragma unroll
    for (int oo = 0; oo < DM; ++oo) {
        float v = (o[oo] - mean) * rs * mnorm_g[oo] + mnorm_b[oo];
        s += v * lin2_w[oo];
    }
    float att = 1.0f / (1.0f + __expf(-s));
    out[g] = 0.25f * att + 0.875f;
}

extern "C" void kernel_launch(void* const* d_in, const int* in_sizes, int n_in,
                              void* d_out, int out_size, void* d_ws, size_t ws_size,
                              hipStream_t stream)
{
    const float* x         = (const float*)d_in[0];
    const float* lin1_w    = (const float*)d_in[1];
    const float* lin1_b    = (const float*)d_in[2];
    const float* ln1_g     = (const float*)d_in[3];
    const float* ln1_b     = (const float*)d_in[4];
    const float* in_proj_w = (const float*)d_in[5];
    const float* conv_w_f  = (const float*)d_in[6];
    const float* conv_b_f  = (const float*)d_in[7];
    const float* xproj_w_f = (const float*)d_in[8];
    const float* dtproj_w_f= (const float*)d_in[9];
    const float* dtproj_b_f= (const float*)d_in[10];
    const float* A_log_f   = (const float*)d_in[11];
    const float* D_f       = (const float*)d_in[12];
    const float* conv_w_r  = (const float*)d_in[13];
    const float* conv_b_r  = (const float*)d_in[14];
    const float* xproj_w_r = (const float*)d_in[15];
    const float* dtproj_w_r= (const float*)d_in[16];
    const float* dtproj_b_r= (const float*)d_in[17];
    const float* A_log_r   = (const float*)d_in[18];
    const float* D_r       = (const float*)d_in[19];
    const float* out_proj_w= (const float*)d_in[20];
    const float* mnorm_g   = (const float*)d_in[21];
    const float* mnorm_b   = (const float*)d_in[22];
    const float* lin2_w    = (const float*)d_in[23];
    const float* lin2_b    = (const float*)d_in[24];

    float* ws   = (float*)d_ws;
    float* avg  = ws;                          // 16384
    float* mx   = ws + 16384;                  // 16384
    float* xz   = ws + 32768;                  // 32*64*512   = 1048576
    float* u_ws = xz + 1048576;                // 2*32*512*32 = 1048576
    float* dt_ws= u_ws + 1048576;              // 1048576
    float* B_ws = dt_ws + 1048576;             // 2*32*512*8  = 262144
    float* C_ws = B_ws + 262144;               // 262144
    float* y_ws = C_ws + 262144;               // 1048576
    (void)ws_size; (void)in_sizes; (void)n_in; (void)out_size;

    pool_kernel<<<BB * CC, 256, 0, stream>>>(x, avg, mx);
    hproj_kernel<<<64 * 4, 256, 0, stream>>>(avg, mx, lin1_w, lin1_b, ln1_g, ln1_b, in_proj_w, xz);
    convproj_kernel<<<BB * 2 * 8, 64, 0, stream>>>(xz, conv_w_f, conv_b_f, xproj_w_f, dtproj_w_f, dtproj_b_f,
                                                   conv_w_r, conv_b_r, xproj_w_r, dtproj_w_r, dtproj_b_r,
                                                   u_ws, dt_ws, B_ws, C_ws);
    scan_kernel<<<BB * 2 * 4, 128, 0, stream>>>(u_ws, dt_ws, B_ws, C_ws, A_log_f, D_f, A_log_r, D_r, y_ws);
    final_kernel<<<256, 64, 0, stream>>>(y_ws, xz, out_proj_w, mnorm_g, mnorm_b, lin2_w, lin2_b,
                                         (float*)d_out);
}

// Round 3
// 91.137 us; speedup vs baseline: 3.2234x; 1.3775x over previous
//
#include <hip/hip_runtime.h>
#include <math.h>

#define BB 32
#define CC 512      // = L (sequence length)
#define HW 4096
#define DM 32       // d_model
#define DI 32       // d_inner
#define DS 8        // d_state
#define KC 4        // conv kernel

__device__ __forceinline__ float siluf(float x) {
    return x / (1.0f + __expf(-x));
}
__device__ __forceinline__ float softplusf(float x) {
    float ax = fabsf(x);
    return fmaxf(x, 0.0f) + log1pf(__expf(-ax));
}

// ---------------- Kernel 1: global avg + max pool over H*W=4096 ----------------
__global__ __launch_bounds__(256) void pool_kernel(const float* __restrict__ x,
                                                   float* __restrict__ avg,
                                                   float* __restrict__ mx) {
    int bc = blockIdx.x;                       // b*512 + c
    const float4* xp = reinterpret_cast<const float4*>(x + (size_t)bc * HW);
    int tid = threadIdx.x;
    float s = 0.f, m = -INFINITY;
#pragma unroll
    for (int r = 0; r < 4; ++r) {
        float4 v = xp[r * 256 + tid];
        s += (v.x + v.y) + (v.z + v.w);
        m = fmaxf(m, fmaxf(fmaxf(v.x, v.y), fmaxf(v.z, v.w)));
    }
    for (int off = 32; off > 0; off >>= 1) {
        s += __shfl_down(s, off);
        m = fmaxf(m, __shfl_down(m, off));
    }
    __shared__ float ss[4], sm[4];
    int wave = tid >> 6;
    if ((tid & 63) == 0) { ss[wave] = s; sm[wave] = m; }
    __syncthreads();
    if (tid == 0) {
        float S = (ss[0] + ss[1]) + (ss[2] + ss[3]);
        float M = fmaxf(fmaxf(sm[0], sm[1]), fmaxf(sm[2], sm[3]));
        avg[bc] = S * (1.0f / HW);
        mx[bc]  = M;
    }
}

// ---------------- Kernel 2: lin1 + layernorm + in_proj -> xz [B][64][512] ----------------
// grid = 64 l-blocks x 4 e-groups; each block computes 16 of the 64 in_proj rows.
__global__ __launch_bounds__(256) void hproj_kernel(
    const float* __restrict__ avg, const float* __restrict__ mx,
    const float* __restrict__ lin1_w, const float* __restrict__ lin1_b,
    const float* __restrict__ ln1_g, const float* __restrict__ ln1_b,
    const float* __restrict__ in_proj_w, float* __restrict__ xz)
{
    int bx = blockIdx.x;
    int lb = bx >> 2, eg = bx & 3;      // l-block 0..63, e-group 0..3
    __shared__ float sW[16 * DM];
    int tid = threadIdx.x;
    for (int i = tid; i < 16 * DM; i += 256) sW[i] = in_proj_w[eg * 16 * DM + i];
    __syncthreads();
    int g = lb * 256 + tid;             // b*512 + l   (l == c)
    int b = g >> 9, l = g & 511;
    float a = avg[g], M = mx[g];
    float h[DM];
    float mean = 0.f;
#pragma unroll
    for (int m_ = 0; m_ < DM; ++m_) {
        h[m_] = a * lin1_w[2 * m_] + M * lin1_w[2 * m_ + 1] + lin1_b[m_];
        mean += h[m_];
    }
    mean *= (1.0f / DM);
    float var = 0.f;
#pragma unroll
    for (int m_ = 0; m_ < DM; ++m_) { float d = h[m_] - mean; var += d * d; }
    var *= (1.0f / DM);
    float rs = rsqrtf(var + 1e-5f);
#pragma unroll
    for (int m_ = 0; m_ < DM; ++m_)
        h[m_] = (h[m_] - mean) * rs * ln1_g[m_] + ln1_b[m_];
#pragma unroll
    for (int e2 = 0; e2 < 16; ++e2) {
        int e = eg * 16 + e2;
        float acc = 0.f;
#pragma unroll
        for (int m_ = 0; m_ < DM; ++m_) acc += h[m_] * sW[e2 * DM + m_];
        xz[(((size_t)b * 64 + e) << 9) + l] = acc;
    }
}

// ------- Kernel 3: conv1d + silu + x_proj + dtproj + scan PHASE 1 (chunk carries) -------
// grid = (b,dir) x 8 chunks of 64 scan positions; block = 256 threads.
// Writes u/dt/B/C (scan-order) and per-chunk carries (aprod, h_local) per (d,n).
#define NCH2 8
#define CHL2 64
__global__ __launch_bounds__(256) void convscan1_kernel(
    const float* __restrict__ xz,
    const float* __restrict__ conv_w_f, const float* __restrict__ conv_b_f,
    const float* __restrict__ xproj_w_f, const float* __restrict__ dtproj_w_f,
    const float* __restrict__ dtproj_b_f,
    const float* __restrict__ conv_w_r, const float* __restrict__ conv_b_r,
    const float* __restrict__ xproj_w_r, const float* __restrict__ dtproj_w_r,
    const float* __restrict__ dtproj_b_r,
    const float* __restrict__ A_log_f, const float* __restrict__ A_log_r,
    float* __restrict__ u_g, float* __restrict__ dt_g,
    float* __restrict__ B_g, float* __restrict__ C_g,
    float* __restrict__ carrA, float* __restrict__ carrH)
{
    int bx = blockIdx.x;
    int bd = bx >> 3, j = bx & 7;       // (b,dir), chunk 0..7
    int b = bd >> 1, dir = bd & 1;
    int tid = threadIdx.x;
    const float* cw = dir ? conv_w_r : conv_w_f;
    const float* cb = dir ? conv_b_r : conv_b_f;
    const float* xw = dir ? xproj_w_r : xproj_w_f;
    const float* dw = dir ? dtproj_w_r : dtproj_w_f;
    const float* db = dir ? dtproj_b_r : dtproj_b_f;
    const float* Alog = dir ? A_log_r : A_log_f;
    const float* xzb = xz + (size_t)b * 64 * 512;   // x-half rows 0..31

    __shared__ float xt[32][69];        // scan-space cols j*64-3 .. j*64+63 (67 used)
    __shared__ float xw_s[18][33];
    __shared__ float u_s[64][33];
    __shared__ float dt_s[64][33];
    __shared__ float B_s[64][9];
    __shared__ float C_s[64][9];
    __shared__ float dtr_s[64][2];

    // stage xz tile (scan order, zero-pad before scan pos 0) + xproj weights
    for (int idx = tid; idx < 32 * 67; idx += 256) {
        int dd = idx / 67, t = idx - dd * 67;
        int sidx = j * CHL2 - 3 + t;
        float v = 0.f;
        if (sidx >= 0) {
            int orig = dir ? (511 - sidx) : sidx;
            v = xzb[(dd << 9) + orig];
        }
        xt[dd][t] = v;
    }
    for (int idx = tid; idx < 18 * 32; idx += 256)
        xw_s[idx >> 5][idx & 31] = xw[idx];
    __syncthreads();

    // conv + silu -> u_s  (thread = (l, d-quarter))
    int l = tid >> 2, gq = tid & 3;
#pragma unroll
    for (int i = 0; i < 8; ++i) {
        int dd = gq * 8 + i;
        float acc = cb[dd];
#pragma unroll
        for (int k = 0; k < KC; ++k) acc += cw[dd * KC + k] * xt[dd][l + k];
        u_s[l][dd] = siluf(acc);
    }
    __syncthreads();

    // projections: 18 outputs per l (2 dt-rank, 8 B, 8 C)
    size_t row8 = ((size_t)bd * 512 + j * CHL2 + l) * 8;
    for (int o = gq; o < 18; o += 4) {
        float acc = 0.f;
#pragma unroll
        for (int m_ = 0; m_ < 32; ++m_) acc += u_s[l][m_] * xw_s[o][m_];
        if (o < 2) dtr_s[l][o] = acc;
        else if (o < 10) { B_s[l][o - 2] = acc; B_g[row8 + (o - 2)] = acc; }
        else             { C_s[l][o - 10] = acc; C_g[row8 + (o - 10)] = acc; }
    }
    __syncthreads();

    // dt = softplus(dtproj) ; write u/dt to global (fully coalesced)
    size_t rowbase = ((size_t)bd * 512 + j * CHL2) * 32;
    for (int idx = tid; idx < CHL2 * 32; idx += 256) {
        int ll = idx >> 5, dd = idx & 31;
        float v = dtr_s[ll][0] * dw[dd * 2] + dtr_s[ll][1] * dw[dd * 2 + 1] + db[dd];
        float sp = softplusf(v);
        dt_s[ll][dd] = sp;
        dt_g[rowbase + idx] = sp;
        u_g[rowbase + idx] = u_s[ll][dd];
    }
    __syncthreads();

    // phase-1 local scan: thread = (d, n)
    int dd = tid >> 3, nn = tid & 7;
    float Aa = -__expf(Alog[tid]);      // Alog[dd*8+nn] == Alog[tid]
    float ap = 1.f, h = 0.f;
#pragma unroll 4
    for (int sl = 0; sl < CHL2; ++sl) {
        float dtv = dt_s[sl][dd];
        float uu  = u_s[sl][dd];
        float bm  = B_s[sl][nn];
        float dA  = __expf(dtv * Aa);
        ap *= dA;
        h = dA * h + dtv * uu * bm;
    }
    carrA[(size_t)bx * 256 + tid] = ap;
    carrH[(size_t)bx * 256 + tid] = h;
}

// ------- Kernel 4: carry combine + scan PHASE 3 + gate + out_proj + LN + head -------
// grid = b x 8 original-l tiles of 64. Forward chunk jt and reverse chunk 7-jt cover
// the SAME original l range -> one block does both dirs and the final head.
// block = 128 threads = (dir, d, n-half); each thread owns 4 n-states.
__global__ __launch_bounds__(128) void scan2final_kernel(
    const float* __restrict__ u_g, const float* __restrict__ dt_g,
    const float* __restrict__ B_g, const float* __restrict__ C_g,
    const float* __restrict__ carrA, const float* __restrict__ carrH,
    const float* __restrict__ A_log_f, const float* __restrict__ D_f,
    const float* __restrict__ A_log_r, const float* __restrict__ D_r,
    const float* __restrict__ xz,
    const float* __restrict__ out_proj_w, const float* __restrict__ mnorm_g,
    const float* __restrict__ mnorm_b, const float* __restrict__ lin2_w,
    const float* __restrict__ lin2_b, float* __restrict__ out)
{
    int bx = blockIdx.x;
    int b = bx >> 3, jt = bx & 7;       // batch, original l-tile
    int tid = threadIdx.x;
    int dir = tid >> 6;                 // 0..1
    int r = tid & 63;
    int dd = r >> 1, nh = r & 1, n0 = nh * 4;
    int bd = b * 2 + dir;
    int jc = dir ? (7 - jt) : jt;       // this dir's chunk covering the tile

    const float* Alog = dir ? A_log_r : A_log_f;
    const float* Dp   = dir ? D_r : D_f;

    float A0 = -__expf(Alog[dd * 8 + n0 + 0]);
    float A1 = -__expf(Alog[dd * 8 + n0 + 1]);
    float A2 = -__expf(Alog[dd * 8 + n0 + 2]);
    float A3 = -__expf(Alog[dd * 8 + n0 + 3]);
    float Dd = Dp[dd];

    // combine carries of preceding chunks -> exact prefix state
    float h0 = 0.f, h1 = 0.f, h2 = 0.f, h3 = 0.f;
    for (int jj = 0; jj < jc; ++jj) {
        size_t cbase = ((size_t)(bd * 8 + jj)) * 256 + dd * 8 + n0;
        float4 av = *reinterpret_cast<const float4*>(carrA + cbase);
        float4 hv = *reinterpret_cast<const float4*>(carrH + cbase);
        h0 = av.x * h0 + hv.x;
        h1 = av.y * h1 + hv.y;
        h2 = av.z * h2 + hv.z;
        h3 = av.w * h3 + hv.w;
    }

    __shared__ float y_s[2][2][64][33];

    size_t sb = (size_t)bd * 512 + jc * CHL2;
#pragma unroll 4
    for (int sl = 0; sl < CHL2; ++sl) {
        size_t s32 = (sb + sl) * 32 + dd;
        float dtv = dt_g[s32];
        float uu  = u_g[s32];
        float4 Bv = *reinterpret_cast<const float4*>(B_g + (sb + sl) * 8 + n0);
        float4 Cv = *reinterpret_cast<const float4*>(C_g + (sb + sl) * 8 + n0);
        float dtu = dtv * uu;
        h0 = __expf(dtv * A0) * h0 + dtu * Bv.x;
        h1 = __expf(dtv * A1) * h1 + dtu * Bv.y;
        h2 = __expf(dtv * A2) * h2 + dtu * Bv.z;
        h3 = __expf(dtv * A3) * h3 + dtu * Bv.w;
        float py = h0 * Cv.x + h1 * Cv.y + h2 * Cv.z + h3 * Cv.w;
        if (nh == 0) py += Dd * uu;
        int ll = dir ? (63 - sl) : sl;  // position within original tile
        y_s[dir][nh][ll][dd] = py;
    }
    __syncthreads();

    // final head: thread = one original l within the tile
    if (tid < 64) {
        int lo = jt * 64 + tid;
        float comb[DI];
#pragma unroll
        for (int d2 = 0; d2 < DI; ++d2) {
            float ys = y_s[0][0][tid][d2] + y_s[0][1][tid][d2]
                     + y_s[1][0][tid][d2] + y_s[1][1][tid][d2];
            float z = xz[(((size_t)(b * 64 + 32 + d2)) << 9) + lo];
            comb[d2] = 0.5f * ys * siluf(z);
        }
        float o[DM];
        float mean = 0.f;
#pragma unroll
        for (int oo = 0; oo < DM; ++oo) {
            float acc = 0.f;
#pragma unroll
            for (int d2 = 0; d2 < DI; ++d2) acc += comb[d2] * out_proj_w[oo * DI + d2];
            o[oo] = acc;
            mean += acc;
        }
        mean *= (1.0f / DM);
        float var = 0.f;
#pragma unroll
        for (int oo = 0; oo < DM; ++oo) { float df = o[oo] - mean; var += df * df; }
        var *= (1.0f / DM);
        float rs = rsqrtf(var + 1e-5f);
        float s = lin2_b[0];
#pragma unroll
        for (int oo = 0; oo < DM; ++oo) {
            float v = (o[oo] - mean) * rs * mnorm_g[oo] + mnorm_b[oo];
            s += v * lin2_w[oo];
        }
        float att = 1.0f / (1.0f + __expf(-s));
        out[(size_t)b * 512 + lo] = 0.25f * att + 0.875f;
    }
}

extern "C" void kernel_launch(void* const* d_in, const int* in_sizes, int n_in,
                              void* d_out, int out_size, void* d_ws, size_t ws_size,
                              hipStream_t stream)
{
    const float* x         = (const float*)d_in[0];
    const float* lin1_w    = (const float*)d_in[1];
    const float* lin1_b    = (const float*)d_in[2];
    const float* ln1_g     = (const float*)d_in[3];
    const float* ln1_b     = (const float*)d_in[4];
    const float* in_proj_w = (const float*)d_in[5];
    const float* conv_w_f  = (const float*)d_in[6];
    const float* conv_b_f  = (const float*)d_in[7];
    const float* xproj_w_f = (const float*)d_in[8];
    const float* dtproj_w_f= (const float*)d_in[9];
    const float* dtproj_b_f= (const float*)d_in[10];
    const float* A_log_f   = (const float*)d_in[11];
    const float* D_f       = (const float*)d_in[12];
    const float* conv_w_r  = (const float*)d_in[13];
    const float* conv_b_r  = (const float*)d_in[14];
    const float* xproj_w_r = (const float*)d_in[15];
    const float* dtproj_w_r= (const float*)d_in[16];
    const float* dtproj_b_r= (const float*)d_in[17];
    const float* A_log_r   = (const float*)d_in[18];
    const float* D_r       = (const float*)d_in[19];
    const float* out_proj_w= (const float*)d_in[20];
    const float* mnorm_g   = (const float*)d_in[21];
    const float* mnorm_b   = (const float*)d_in[22];
    const float* lin2_w    = (const float*)d_in[23];
    const float* lin2_b    = (const float*)d_in[24];

    float* ws   = (float*)d_ws;
    float* avg  = ws;                          // 16384
    float* mx   = ws + 16384;                  // 16384
    float* xz   = ws + 32768;                  // 32*64*512   = 1048576
    float* u_g  = xz + 1048576;                // 2*32*512*32 = 1048576
    float* dt_g = u_g + 1048576;               // 1048576
    float* B_g  = dt_g + 1048576;              // 2*32*512*8  = 262144
    float* C_g  = B_g + 262144;                // 262144
    float* carrA= C_g + 262144;                // 64*8*256    = 131072
    float* carrH= carrA + 131072;              // 131072
    (void)ws_size; (void)in_sizes; (void)n_in; (void)out_size;

    pool_kernel<<<BB * CC, 256, 0, stream>>>(x, avg, mx);
    hproj_kernel<<<64 * 4, 256, 0, stream>>>(avg, mx, lin1_w, lin1_b, ln1_g, ln1_b, in_proj_w, xz);
    convscan1_kernel<<<BB * 2 * NCH2, 256, 0, stream>>>(
        xz, conv_w_f, conv_b_f, xproj_w_f, dtproj_w_f, dtproj_b_f,
        conv_w_r, conv_b_r, xproj_w_r, dtproj_w_r, dtproj_b_r,
        A_log_f, A_log_r, u_g, dt_g, B_g, C_g, carrA, carrH);
    scan2final_kernel<<<BB * NCH2, 128, 0, stream>>>(
        u_g, dt_g, B_g, C_g, carrA, carrH,
        A_log_f, D_f, A_log_r, D_r, xz,
        out_proj_w, mnorm_g, mnorm_b, lin2_w, lin2_b, (float*)d_out);
}